// Round 2
// baseline (193.867 us; speedup 1.0000x reference)
//
#include <hip/hip_runtime.h>
#include <math.h>

// Shapes are fixed by the reference: x [B=16, C=512, N=4096] fp32.
constexpr int B  = 16;
constexpr int C  = 512;
constexpr int N  = 4096;
constexpr int CR = 128;   // C/4

__device__ __forceinline__ float sigmoidf_(float v) {
    return 1.0f / (1.0f + __expf(-v));
}

// ---------------------------------------------------------------------------
// k_prep: fold BN affine into w3 and transpose: w3t[c][o] = w3[o][c] * inv[o]
//         bias2[o] = b3[o]*inv[o] + beta[o] - mean[o]*inv[o]
// ---------------------------------------------------------------------------
__global__ __launch_bounds__(256) void k_prep(
    const float* __restrict__ w3, const float* __restrict__ b3,
    const float* __restrict__ gamma, const float* __restrict__ beta,
    const float* __restrict__ mean, const float* __restrict__ var,
    float* __restrict__ w3t, float* __restrict__ bias2)
{
    int idx = blockIdx.x * 256 + threadIdx.x;   // 0 .. CR*C-1 (65536)
    int o = idx >> 9;        // /C
    int c = idx & (C - 1);
    float inv = gamma[o] / sqrtf(var[o] + 1e-5f);
    w3t[c * CR + o] = w3[idx] * inv;
    if (idx < CR) {
        float iv = gamma[idx] / sqrtf(var[idx] + 1e-5f);
        bias2[idx] = b3[idx] * iv + beta[idx] - mean[idx] * iv;
    }
}

// ---------------------------------------------------------------------------
// k_pool: pooled[b][c] = mean_n x[b][c][n].  One wave per row.
// ---------------------------------------------------------------------------
__global__ __launch_bounds__(256) void k_pool(
    const float* __restrict__ x, float* __restrict__ pooled)
{
    int w    = threadIdx.x >> 6;
    int lane = threadIdx.x & 63;
    int row  = blockIdx.x * 4 + w;              // b*C + c, 0..8191
    const float4* xr = (const float4*)(x + (size_t)row * N);
    float s = 0.f;
    #pragma unroll
    for (int i = 0; i < 16; ++i) {
        float4 v = xr[i * 64 + lane];
        s += v.x + v.y + v.z + v.w;
    }
    #pragma unroll
    for (int off = 32; off; off >>= 1) s += __shfl_xor(s, off, 64);
    if (lane == 0) pooled[row] = s * (1.0f / N);
}

// ---------------------------------------------------------------------------
// k_ca: channel-attention MLP.  One block (128 threads) per batch element.
//   h  = relu(pooled @ w1^T + b1)   [CR]
//   ca = sigmoid(h @ w2^T + b2)     [C]
// ---------------------------------------------------------------------------
__global__ __launch_bounds__(128) void k_ca(
    const float* __restrict__ pooled,
    const float* __restrict__ w1, const float* __restrict__ b1,
    const float* __restrict__ w2, const float* __restrict__ b2,
    float* __restrict__ ca)
{
    __shared__ float ps[C];
    __shared__ float hs[CR];
    int b = blockIdx.x, t = threadIdx.x;
    #pragma unroll
    for (int i = 0; i < 4; ++i) ps[t + i * 128] = pooled[b * C + t + i * 128];
    __syncthreads();

    float acc = b1[t];
    const float4* wr = (const float4*)(w1 + t * C);
    const float4* pr = (const float4*)ps;
    #pragma unroll 4
    for (int i = 0; i < C / 4; ++i) {
        float4 wv = wr[i], pv = pr[i];
        acc += wv.x * pv.x + wv.y * pv.y + wv.z * pv.z + wv.w * pv.w;
    }
    hs[t] = fmaxf(acc, 0.f);
    __syncthreads();

    #pragma unroll
    for (int k = 0; k < 4; ++k) {
        int c2 = t + k * 128;
        float a = b2[c2];
        const float4* w2r = (const float4*)(w2 + c2 * CR);
        const float4* hr  = (const float4*)hs;
        #pragma unroll 4
        for (int i = 0; i < CR / 4; ++i) {
            float4 wv = w2r[i], hv = hr[i];
            a += wv.x * hv.x + wv.y * hv.y + wv.z * hv.z + wv.w * hv.w;
        }
        ca[b * C + c2] = sigmoidf_(a);
    }
}

// ---------------------------------------------------------------------------
// k_main: per (b, 128-col n-tile):
//   GEMM  h2pre[128][128] = w3t^T @ (x*ca) tile   (K = 512, chunked by 32)
//   sa[n] = sigmoid(sum_o w4[o]*relu(h2pre[o][n]+bias2[o]) + b4)
//   out   = x * (1 + ca[c]*sa[n])
// 256 threads as 16x16, each computing an 8x8 register tile.
// ---------------------------------------------------------------------------
__global__ __launch_bounds__(256) void k_main(
    const float* __restrict__ x,
    const float* __restrict__ ca, const float* __restrict__ w3t,
    const float* __restrict__ bias2, const float* __restrict__ w4,
    const float* __restrict__ b4, float* __restrict__ out)
{
    __shared__ float xs[32][128];     // (x*ca) chunk  [k][n]
    __shared__ float ws[32][128];     // w3t chunk     [k][o]
    __shared__ float ca_s[C];
    __shared__ float red[16][128];
    __shared__ float sa_s[128];
    __shared__ float bias2_s[CR];
    __shared__ float w4_s[CR];

    const int t  = threadIdx.x;
    const int b  = blockIdx.y;
    const int n0 = blockIdx.x * 128;
    const int tx = t & 15;            // n sub-block
    const int ty = t >> 4;            // o sub-block

    ca_s[t]       = ca[b * C + t];
    ca_s[t + 256] = ca[b * C + t + 256];
    if (t < CR) { bias2_s[t] = bias2[t]; w4_s[t] = w4[t]; }
    __syncthreads();

    float acc[8][8];
    #pragma unroll
    for (int i = 0; i < 8; ++i)
        #pragma unroll
        for (int j = 0; j < 8; ++j) acc[i][j] = 0.f;

    const size_t xbase = (size_t)b * C * N + n0;

    for (int ck = 0; ck < 16; ++ck) {
        const int c0 = ck * 32;
        #pragma unroll
        for (int p = 0; p < 4; ++p) {
            int f4 = p * 256 + t;          // 0..1023
            int cc = f4 >> 5;              // row within chunk (0..31)
            int n4 = f4 & 31;              // float4 within row
            float4 v = *(const float4*)(x + xbase + (size_t)(c0 + cc) * N + n4 * 4);
            float s = ca_s[c0 + cc];
            v.x *= s; v.y *= s; v.z *= s; v.w *= s;
            *(float4*)&xs[cc][n4 * 4] = v;
            float4 w = *(const float4*)(w3t + (c0 + cc) * CR + n4 * 4);
            *(float4*)&ws[cc][n4 * 4] = w;
        }
        __syncthreads();
        #pragma unroll
        for (int k = 0; k < 32; ++k) {
            float4 a0 = *(const float4*)&ws[k][ty * 8];
            float4 a1 = *(const float4*)&ws[k][ty * 8 + 4];
            float4 x0 = *(const float4*)&xs[k][tx * 4];
            float4 x1 = *(const float4*)&xs[k][64 + tx * 4];
            float av[8] = {a0.x, a0.y, a0.z, a0.w, a1.x, a1.y, a1.z, a1.w};
            float xv[8] = {x0.x, x0.y, x0.z, x0.w, x1.x, x1.y, x1.z, x1.w};
            #pragma unroll
            for (int i = 0; i < 8; ++i)
                #pragma unroll
                for (int j = 0; j < 8; ++j)
                    acc[i][j] = fmaf(av[i], xv[j], acc[i][j]);
        }
        __syncthreads();
    }

    // bias + relu + w4 dot (partial over this thread's 8 o's)
    float p0[8];
    #pragma unroll
    for (int j = 0; j < 8; ++j) p0[j] = 0.f;
    #pragma unroll
    for (int i = 0; i < 8; ++i) {
        int o = ty * 8 + i;
        float bb = bias2_s[o], wv = w4_s[o];
        #pragma unroll
        for (int j = 0; j < 8; ++j) {
            float h = fmaxf(acc[i][j] + bb, 0.f);
            p0[j] = fmaf(wv, h, p0[j]);
        }
    }
    #pragma unroll
    for (int j = 0; j < 4; ++j) {
        red[ty][tx * 4 + j]      = p0[j];
        red[ty][64 + tx * 4 + j] = p0[4 + j];
    }
    __syncthreads();
    if (t < 128) {
        float s = 0.f;
        #pragma unroll
        for (int r = 0; r < 16; ++r) s += red[r][t];
        sa_s[t] = sigmoidf_(s + b4[0]);
    }
    __syncthreads();

    // epilogue: out = x * (1 + ca[c]*sa[n]), re-read x (L2-hot).
    // Full tile is C*128 floats = 16384 float4s -> 64 iterations of 256 thr.
    #pragma unroll 4
    for (int it = 0; it < 64; ++it) {
        int f4 = it * 256 + t;             // 0..16383
        int c  = f4 >> 5;                  // 0..511
        int n4 = f4 & 31;
        const size_t off = xbase + (size_t)c * N + n4 * 4;
        float4 v = *(const float4*)(x + off);
        float cav = ca_s[c];
        float4 sv = *(const float4*)&sa_s[n4 * 4];
        float4 o4;
        o4.x = v.x * fmaf(cav, sv.x, 1.0f);
        o4.y = v.y * fmaf(cav, sv.y, 1.0f);
        o4.z = v.z * fmaf(cav, sv.z, 1.0f);
        o4.w = v.w * fmaf(cav, sv.w, 1.0f);
        *(float4*)(out + off) = o4;
    }
}

extern "C" void kernel_launch(void* const* d_in, const int* in_sizes, int n_in,
                              void* d_out, int out_size, void* d_ws, size_t ws_size,
                              hipStream_t stream)
{
    const float* x   = (const float*)d_in[0];
    const float* w1  = (const float*)d_in[1];
    const float* b1  = (const float*)d_in[2];
    const float* w2  = (const float*)d_in[3];
    const float* b2  = (const float*)d_in[4];
    const float* w3  = (const float*)d_in[5];
    const float* b3  = (const float*)d_in[6];
    const float* g   = (const float*)d_in[7];
    const float* be  = (const float*)d_in[8];
    const float* mn  = (const float*)d_in[9];
    const float* vr  = (const float*)d_in[10];
    const float* w4  = (const float*)d_in[11];
    const float* b4  = (const float*)d_in[12];
    float* out = (float*)d_out;

    float* ws     = (float*)d_ws;
    float* pooled = ws;             // 8192 floats
    float* ca     = ws + 8192;      // 8192 floats
    float* bias2  = ws + 16384;     // 128 floats (+pad)
    float* w3t    = ws + 16640;     // 65536 floats

    k_prep<<<CR * C / 256, 256, 0, stream>>>(w3, b3, g, be, mn, vr, w3t, bias2);
    k_pool<<<B * C / 4, 256, 0, stream>>>(x, pooled);
    k_ca<<<B, 128, 0, stream>>>(pooled, w1, b1, w2, b2, ca);
    dim3 g3(N / 128, B);
    k_main<<<g3, 256, 0, stream>>>(x, ca, w3t, bias2, w4, b4, out);
}

// Round 3
// 126.563 us; speedup vs baseline: 1.5318x; 1.5318x over previous
//
#include <hip/hip_runtime.h>
#include <math.h>

// Shapes fixed by the reference: x [B=16, C=512, N=4096] fp32.
constexpr int B  = 16;
constexpr int C  = 512;
constexpr int N  = 4096;
constexpr int CR = 128;   // C/4
constexpr int NT = 64;    // n-tile per k_main block
constexpr int KC = 64;    // c-chunk per staging step

typedef __attribute__((ext_vector_type(8))) short bf16x8;
typedef __attribute__((ext_vector_type(4))) float f32x4;

__device__ __forceinline__ float sigmoidf_(float v) {
    return 1.0f / (1.0f + __expf(-v));
}
// fp32 -> bf16 round-to-nearest-even
__device__ __forceinline__ unsigned short f2bf(float f) {
    unsigned u = __float_as_uint(f);
    u += 0x7fffu + ((u >> 16) & 1u);
    return (unsigned short)(u >> 16);
}

// ---------------------------------------------------------------------------
// k_prep: w3s[o][c] = bf16(w3[o][c] * inv[o]), stored CHUNK-MAJOR and
// XOR-swizzled so k_main can stage each 16KB chunk with linear 16B copies:
//   byte(ck, o, cl) = ck*16384 + ((o*128 + cl*2) ^ ((o&7)<<4))
// bias2[o] = b3[o]*inv[o] + beta[o] - mean[o]*inv[o]
// ---------------------------------------------------------------------------
__global__ __launch_bounds__(256) void k_prep(
    const float* __restrict__ w3, const float* __restrict__ b3,
    const float* __restrict__ gamma, const float* __restrict__ beta,
    const float* __restrict__ mean, const float* __restrict__ var,
    unsigned short* __restrict__ w3s, float* __restrict__ bias2)
{
    int idx = blockIdx.x * 256 + threadIdx.x;   // 0..8191, 8 elems each
    int o  = idx >> 6;                          // 0..127
    int g  = idx & 63;
    int ck = g >> 3;                            // chunk 0..7
    int c8 = (g & 7) * 8;                       // c within chunk
    int c  = ck * KC + c8;
    float inv = gamma[o] * rsqrtf(var[o] + 1e-5f);
    float4 a = *(const float4*)(w3 + o * C + c);
    float4 bq = *(const float4*)(w3 + o * C + c + 4);
    unsigned r0 = (unsigned)f2bf(a.x * inv) | ((unsigned)f2bf(a.y * inv) << 16);
    unsigned r1 = (unsigned)f2bf(a.z * inv) | ((unsigned)f2bf(a.w * inv) << 16);
    unsigned r2 = (unsigned)f2bf(bq.x * inv) | ((unsigned)f2bf(bq.y * inv) << 16);
    unsigned r3 = (unsigned)f2bf(bq.z * inv) | ((unsigned)f2bf(bq.w * inv) << 16);
    int byte = (o * 128 + c8 * 2) ^ ((o & 7) << 4);
    *(uint4*)((char*)w3s + ck * 16384 + byte) = make_uint4(r0, r1, r2, r3);
    if (idx < CR) {
        float iv = gamma[idx] * rsqrtf(var[idx] + 1e-5f);
        bias2[idx] = b3[idx] * iv + beta[idx] - mean[idx] * iv;
    }
}

// ---------------------------------------------------------------------------
// k_pool: pooled[b][c] = mean_n x[b][c][n].  One wave per row.
// ---------------------------------------------------------------------------
__global__ __launch_bounds__(256) void k_pool(
    const float* __restrict__ x, float* __restrict__ pooled)
{
    int w    = threadIdx.x >> 6;
    int lane = threadIdx.x & 63;
    int row  = blockIdx.x * 4 + w;              // b*C + c
    const float4* xr = (const float4*)(x + (size_t)row * N);
    float s = 0.f;
    #pragma unroll
    for (int i = 0; i < 16; ++i) {
        float4 v = xr[i * 64 + lane];
        s += v.x + v.y + v.z + v.w;
    }
    #pragma unroll
    for (int off = 32; off; off >>= 1) s += __shfl_xor(s, off, 64);
    if (lane == 0) pooled[row] = s * (1.0f / N);
}

// ---------------------------------------------------------------------------
// k_ca: channel-attention MLP.  One block (128 threads) per batch element.
// ---------------------------------------------------------------------------
__global__ __launch_bounds__(128) void k_ca(
    const float* __restrict__ pooled,
    const float* __restrict__ w1, const float* __restrict__ b1,
    const float* __restrict__ w2, const float* __restrict__ b2,
    float* __restrict__ ca)
{
    __shared__ float ps[C];
    __shared__ float hs[CR];
    int b = blockIdx.x, t = threadIdx.x;
    #pragma unroll
    for (int i = 0; i < 4; ++i) ps[t + i * 128] = pooled[b * C + t + i * 128];
    __syncthreads();

    float acc = b1[t];
    const float4* wr = (const float4*)(w1 + t * C);
    const float4* pr = (const float4*)ps;
    #pragma unroll 4
    for (int i = 0; i < C / 4; ++i) {
        float4 wv = wr[i], pv = pr[i];
        acc += wv.x * pv.x + wv.y * pv.y + wv.z * pv.z + wv.w * pv.w;
    }
    hs[t] = fmaxf(acc, 0.f);
    __syncthreads();

    #pragma unroll
    for (int k = 0; k < 4; ++k) {
        int c2 = t + k * 128;
        float a = b2[c2];
        const float4* w2r = (const float4*)(w2 + c2 * CR);
        const float4* hr  = (const float4*)hs;
        #pragma unroll 4
        for (int i = 0; i < CR / 4; ++i) {
            float4 wv = w2r[i], hv = hr[i];
            a += wv.x * hv.x + wv.y * hv.y + wv.z * hv.z + wv.w * hv.w;
        }
        ca[b * C + c2] = sigmoidf_(a);
    }
}

// ---------------------------------------------------------------------------
// k_main (bf16 MFMA): per (b, 64-col n-tile):
//   h2[128 o][64 n] = w3s @ (x*ca) over c=512 via mfma_f32_16x16x32_bf16
//   sa[n] = sigmoid(sum_o w4[o]*relu(h2+bias2) + b4)
//   out   = x * (1 + ca[c]*sa[n])
// 4 waves as 2(o) x 2(n); each wave owns [64 o][32 n] = 4x2 fragments.
// LDS tiles XOR-swizzled: byte ^= (row&7)<<4  (row = o for w, n for xT).
// ---------------------------------------------------------------------------
__global__ __launch_bounds__(256) void k_main(
    const float* __restrict__ x, const float* __restrict__ ca,
    const unsigned short* __restrict__ w3s, const float* __restrict__ bias2,
    const float* __restrict__ w4, const float* __restrict__ b4,
    float* __restrict__ out)
{
    __shared__ __align__(16) short lds_w[CR * KC];   // 16 KB, swizzled [o][c]
    __shared__ __align__(16) short lds_x[NT * KC];   //  8 KB, swizzled [n][c]
    __shared__ float ca_s[C];
    __shared__ __align__(16) float sa_s[NT];
    __shared__ float red[2][NT];
    __shared__ float bias2_s[CR];
    __shared__ float w4_s[CR];

    const int t    = threadIdx.x;
    const int lane = t & 63;
    const int w    = t >> 6;
    const int b    = blockIdx.y;
    const int n0   = blockIdx.x * NT;
    const int wo   = (w & 1) * 64;     // wave o-base
    const int wn   = (w >> 1) * 32;    // wave n-base

    ca_s[t]       = ca[b * C + t];
    ca_s[t + 256] = ca[b * C + t + 256];
    if (t < CR) { bias2_s[t] = bias2[t]; w4_s[t] = w4[t]; }

    const size_t xbase = (size_t)b * C * N + n0;

    f32x4 acc[4][2];
    #pragma unroll
    for (int i = 0; i < 4; ++i) { acc[i][0] = (f32x4)0.f; acc[i][1] = (f32x4)0.f; }

    const int ng = t & 31;   // x-stage: n pair = 2*ng
    const int cg = t >> 5;   // x-stage: c sub  = cg*8

    for (int ck = 0; ck < C / KC; ++ck) {
        const int c0 = ck * KC;
        __syncthreads();
        // ---- stage w3s chunk: pre-swizzled in global -> linear 16B copies
        const char* wsrc = (const char*)w3s + ck * 16384;
        #pragma unroll
        for (int i = 0; i < 4; ++i)
            *(uint4*)((char*)lds_w + i * 4096 + t * 16) =
                *(const uint4*)(wsrc + i * 4096 + t * 16);
        // ---- stage x chunk: transpose [c][n] -> [n][c], scale by ca, bf16
        {
            float2 v[8];
            #pragma unroll
            for (int ci = 0; ci < 8; ++ci)
                v[ci] = *(const float2*)(x + xbase + (size_t)(c0 + cg * 8 + ci) * N + 2 * ng);
            unsigned q0[4], q1[4];
            #pragma unroll
            for (int h = 0; h < 4; ++h) {
                float s0 = ca_s[c0 + cg * 8 + 2 * h];
                float s1 = ca_s[c0 + cg * 8 + 2 * h + 1];
                q0[h] = (unsigned)f2bf(v[2 * h].x * s0) | ((unsigned)f2bf(v[2 * h + 1].x * s1) << 16);
                q1[h] = (unsigned)f2bf(v[2 * h].y * s0) | ((unsigned)f2bf(v[2 * h + 1].y * s1) << 16);
            }
            int nl0 = 2 * ng, nl1 = 2 * ng + 1;
            int a0 = (nl0 * 128 + cg * 16) ^ ((nl0 & 7) << 4);
            int a1 = (nl1 * 128 + cg * 16) ^ ((nl1 & 7) << 4);
            *(uint4*)((char*)lds_x + a0) = make_uint4(q0[0], q0[1], q0[2], q0[3]);
            *(uint4*)((char*)lds_x + a1) = make_uint4(q1[0], q1[1], q1[2], q1[3]);
        }
        __syncthreads();
        // ---- 2 K-steps of 32
        #pragma unroll
        for (int kk = 0; kk < 2; ++kk) {
            bf16x8 af[4], bfr[2];
            #pragma unroll
            for (int i = 0; i < 4; ++i) {
                int ar = wo + i * 16 + (lane & 15);
                int ab = (ar * 128 + kk * 64 + (lane >> 4) * 16) ^ ((ar & 7) << 4);
                af[i] = *(const bf16x8*)((const char*)lds_w + ab);
            }
            #pragma unroll
            for (int j = 0; j < 2; ++j) {
                int br = wn + j * 16 + (lane & 15);
                int bb = (br * 128 + kk * 64 + (lane >> 4) * 16) ^ ((br & 7) << 4);
                bfr[j] = *(const bf16x8*)((const char*)lds_x + bb);
            }
            #pragma unroll
            for (int i = 0; i < 4; ++i)
                #pragma unroll
                for (int j = 0; j < 2; ++j)
                    acc[i][j] = __builtin_amdgcn_mfma_f32_16x16x32_bf16(af[i], bfr[j], acc[i][j], 0, 0, 0);
        }
    }

    // ---- sa: per-lane partial over this wave's 64 o's, then cross-lane
    // C/D layout: col = lane&15 (n), row = (lane>>4)*4 + reg (o)
    #pragma unroll
    for (int j = 0; j < 2; ++j) {
        float p = 0.f;
        #pragma unroll
        for (int i = 0; i < 4; ++i) {
            #pragma unroll
            for (int r = 0; r < 4; ++r) {
                int o = wo + i * 16 + (lane >> 4) * 4 + r;
                float hval = acc[i][j][r] + bias2_s[o];
                p = fmaf(w4_s[o], fmaxf(hval, 0.f), p);
            }
        }
        p += __shfl_xor(p, 16, 64);
        p += __shfl_xor(p, 32, 64);
        if (lane < 16) red[w & 1][wn + j * 16 + lane] = p;
    }
    __syncthreads();
    if (t < NT) sa_s[t] = sigmoidf_(red[0][t] + red[1][t] + b4[0]);
    __syncthreads();

    // ---- epilogue: out = x * (1 + ca[c]*sa[n]); x re-read is L2/L3-hot
    #pragma unroll 4
    for (int it = 0; it < 32; ++it) {
        int f4 = it * 256 + t;          // 0..8191
        int c  = f4 >> 4;               // 0..511
        int n4 = f4 & 15;
        size_t off = xbase + (size_t)c * N + n4 * 4;
        float4 v = *(const float4*)(x + off);
        float cav = ca_s[c];
        float4 sv = *(const float4*)&sa_s[n4 * 4];
        float4 o4;
        o4.x = v.x * fmaf(cav, sv.x, 1.0f);
        o4.y = v.y * fmaf(cav, sv.y, 1.0f);
        o4.z = v.z * fmaf(cav, sv.z, 1.0f);
        o4.w = v.w * fmaf(cav, sv.w, 1.0f);
        *(float4*)(out + off) = o4;
    }
}

extern "C" void kernel_launch(void* const* d_in, const int* in_sizes, int n_in,
                              void* d_out, int out_size, void* d_ws, size_t ws_size,
                              hipStream_t stream)
{
    const float* x   = (const float*)d_in[0];
    const float* w1  = (const float*)d_in[1];
    const float* b1  = (const float*)d_in[2];
    const float* w2  = (const float*)d_in[3];
    const float* b2  = (const float*)d_in[4];
    const float* w3  = (const float*)d_in[5];
    const float* b3  = (const float*)d_in[6];
    const float* g   = (const float*)d_in[7];
    const float* be  = (const float*)d_in[8];
    const float* mn  = (const float*)d_in[9];
    const float* vr  = (const float*)d_in[10];
    const float* w4  = (const float*)d_in[11];
    const float* b4  = (const float*)d_in[12];
    float* out = (float*)d_out;

    float* ws     = (float*)d_ws;
    float* pooled = ws;                                // 8192 floats
    float* ca     = ws + 8192;                         // 8192 floats
    float* bias2  = ws + 16384;                        // 128 floats (+pad)
    unsigned short* w3s = (unsigned short*)(ws + 16640); // 65536 bf16 (128 KB)

    k_prep<<<32, 256, 0, stream>>>(w3, b3, g, be, mn, vr, w3s, bias2);
    k_pool<<<B * C / 4, 256, 0, stream>>>(x, pooled);
    k_ca<<<B, 128, 0, stream>>>(pooled, w1, b1, w2, b2, ca);
    dim3 g3(N / NT, B);
    k_main<<<g3, 256, 0, stream>>>(x, ca, w3s, bias2, w4, b4, out);
}